// Round 3
// baseline (104.814 us; speedup 1.0000x reference)
//
#include <hip/hip_runtime.h>
#include <hip/hip_fp16.h>
#include <math.h>

constexpr int NFFT = 256;
constexpr int HOP  = 216;
constexpr int PAD  = 20;

typedef float v2f __attribute__((ext_vector_type(2)));

// LDS layout in v2f units (8 B each); phases alias time-disjointly:
//  plane [0..1152)   : 4 fm x (16 rows x stride 18 v2f)   -- fwd/inv transposes
//  C     [0..576)    : skewed complex c, stride 288/frame  (aliases plane)
//  IPAD  [576..912)  : skewed padded intensity (floats [1152..1824)), 336 floats/frame
//  H     [1152..1234): {h,h} splat tables (41 re + 41 im)
//  EXB   [1152..1232): fr0 tail exchange (aliases retired H, used after FIR)
constexpr int RS    = 18;     // transpose row stride (v2f)
constexpr int PLF   = 288;    // per-fm plane size (v2f)
constexpr int CFS   = 288;    // C stride per frame (v2f)
constexpr int IPB_F = 1152;   // IPAD base (float idx)
constexpr int IPS_F = 336;    // IPAD stride per frame (floats)
constexpr int HRB   = 1152;   // hr2 table base (v2f idx)
constexpr int HIB   = 1193;   // hi2 table base (v2f idx)
constexpr int EXB   = 1152;   // exchange base (v2f idx), aliases retired H tables
constexpr int SMV   = 1234;   // total v2f = 9872 B

__device__ __forceinline__ v2f mkv2(float a, float b) { v2f r; r.x = a; r.y = b; return r; }

// complex mul: {a.x*b.x - a.y*b.y, a.x*b.y + a.y*b.x} -> pk_mul + pk_fma (op_sel/neg folded)
__device__ __forceinline__ v2f cmul2(v2f a, v2f b) {
    return a.xx * b + a.yy * mkv2(-b.y, b.x);
}

constexpr float TC16[10] = {1.f, 0.92387953f, 0.70710678f, 0.38268343f, 0.f,
                            -0.38268343f, -0.70710678f, -0.92387953f, -1.f, -0.92387953f};
constexpr float TS16[10] = {0.f, 0.38268343f, 0.70710678f, 0.92387953f, 1.f,
                            0.92387953f, 0.70710678f, 0.38268343f, 0.f, -0.38268343f};

// In-register 16-point DFT on (re,im) pairs, natural order in/out.
template<int SGN>
__device__ __forceinline__ void fft16v(v2f x[16]) {
    v2f t[4][4];
    #pragma unroll
    for (int n1 = 0; n1 < 4; ++n1) {
        v2f a = x[n1], b = x[n1 + 4], c = x[n1 + 8], d = x[n1 + 12];
        v2f A = a + c, B = a - c, C = b + d, D = b - d;
        v2f jD = mkv2(-D.y, D.x);
        t[n1][0] = A + C;
        t[n1][2] = A - C;
        if (SGN < 0) { t[n1][1] = B - jD; t[n1][3] = B + jD; }
        else         { t[n1][1] = B + jD; t[n1][3] = B - jD; }
    }
    #pragma unroll
    for (int n1 = 1; n1 < 4; ++n1) {
        #pragma unroll
        for (int k2 = 1; k2 < 4; ++k2) {
            const int m = n1 * k2;
            const float wr = TC16[m], wi = (float)SGN * TS16[m];
            v2f v = t[n1][k2];
            t[n1][k2] = wr * v + wi * mkv2(-v.y, v.x);
        }
    }
    #pragma unroll
    for (int k2 = 0; k2 < 4; ++k2) {
        v2f a = t[0][k2], b = t[1][k2], c = t[2][k2], d = t[3][k2];
        v2f A = a + c, B = a - c, C = b + d, D = b - d;
        v2f jD = mkv2(-D.y, D.x);
        x[k2]      = A + C;
        x[k2 + 8]  = A - C;
        if (SGN < 0) { x[k2 + 4] = B - jD; x[k2 + 12] = B + jD; }
        else         { x[k2 + 4] = B + jD; x[k2 + 12] = B - jD; }
    }
}

// x[k] *= w1^k via power tree + 4 parallel chains.
__device__ __forceinline__ void twiddle4(v2f x[16], v2f w1) {
    const v2f w2 = cmul2(w1, w1);
    const v2f w4 = cmul2(w2, w2);
    const v2f w8 = cmul2(w4, w4);
    x[1] = cmul2(x[1], w1);
    x[2] = cmul2(x[2], w2);
    x[3] = cmul2(x[3], cmul2(w2, w1));
    v2f wk = w4;
    x[4] = cmul2(x[4], wk);
    wk = cmul2(wk, w1); x[5] = cmul2(x[5], wk);
    wk = cmul2(wk, w1); x[6] = cmul2(x[6], wk);
    wk = cmul2(wk, w1); x[7] = cmul2(x[7], wk);
    v2f wm = w8;
    x[8] = cmul2(x[8], wm);
    wm = cmul2(wm, w1); x[9]  = cmul2(x[9],  wm);
    wm = cmul2(wm, w1); x[10] = cmul2(x[10], wm);
    wm = cmul2(wm, w1); x[11] = cmul2(x[11], wm);
    v2f wn = cmul2(w8, w4);
    x[12] = cmul2(x[12], wn);
    wn = cmul2(wn, w1); x[13] = cmul2(x[13], wn);
    wn = cmul2(wn, w1); x[14] = cmul2(x[14], wn);
    wn = cmul2(wn, w1); x[15] = cmul2(x[15], wn);
}

// Zero only the EVEN-s overlap stripes (the only remaining atomicAdd targets).
__global__ __launch_bounds__(256)
void zero_overlap(float4* __restrict__ out4, int B, int steps, int Lout) {
    const int nb = (steps - 1) / 2;            // even boundaries s = 2,4,...,2*nb
    const int total = B * nb * 40;
    for (int idx = blockIdx.x * 256 + threadIdx.x; idx < total; idx += gridDim.x * 256) {
        const int j  = idx / 40;
        const int r4 = idx - j * 40;
        const int b  = j / nb;
        const int k  = j - b * nb;
        const int s  = 2 * (k + 1);
        out4[(size_t)b * Lout + (size_t)s * HOP - PAD + r4] = make_float4(0.f, 0.f, 0.f, 0.f);
    }
}

// ONE WAVE per block: 64 threads = 2 frames x 2 modes x 16 lanes.
// The two frames are always (b, s) and (b, s+1): the odd-s boundary between
// them is resolved in-block via LDS (no atomics, no pre-zeroing).
__global__ __launch_bounds__(64)
void eq_pbc_kernel(const float* __restrict__ x_real,
                   const float* __restrict__ x_imag,
                   const float* __restrict__ task_info,
                   const float* __restrict__ h_real,
                   const float* __restrict__ h_imag,
                   float* __restrict__ out,
                   int B, int L, int steps)
{
    __shared__ __align__(16) v2f SM2[SMV];
    float* SMf = (float*)SM2;

    const int tid = threadIdx.x;
    const int i   = tid & 15;
    const int fm  = tid >> 4;     // 0..3
    const int fr  = fm >> 1;      // frame-local 0..1
    const int md  = fm & 1;

    const int G = B * steps;
    int g = blockIdx.x * 2 + fr;
    const bool valid = (g < G);
    if (!valid) g = G - 1;
    const int b  = g / steps;
    const int s  = g - b * steps;
    const int l0 = s * HOP;

    // stage {h,h} splat tables once (read by FIR after >=2 barriers)
    if (tid < 41) {
        const float hr = h_real[tid], hi = h_imag[tid];
        SM2[HRB + tid] = mkv2(hr, hr);
        SM2[HIB + tid] = mkv2(hi, hi);
    }

    float sb, cb;
    __sincosf(-6.2831853071795864f * (1.0f / 256.0f) * (float)i, &sb, &cb);

    // ---- load: thread holds x[l0 + i + 16*n2] for its (frame, mode) ----
    v2f X[16];
    {
        const size_t base = ((size_t)b * L + l0) * 2 + (size_t)(2 * i + md);
        #pragma unroll
        for (int n2 = 0; n2 < 16; ++n2)
            X[n2] = mkv2(x_real[base + 32 * n2], x_imag[base + 32 * n2]);
    }

    // ---- forward step A + twiddle W256^{i*k2} ----
    fft16v<-1>(X);
    twiddle4(X, mkv2(cb, sb));

    // ---- forward transpose (float2 plane, float4 row writes) ----
    const int tb2 = fm * PLF;
    {
        float4* rowp = (float4*)&SM2[tb2 + i * RS];
        #pragma unroll
        for (int k = 0; k < 16; k += 2)
            rowp[k >> 1] = make_float4(X[k].x, X[k].y, X[k + 1].x, X[k + 1].y);
    }
    __syncthreads();
    #pragma unroll
    for (int n1 = 0; n1 < 16; ++n1) X[n1] = SM2[tb2 + n1 * RS + i];

    // ---- forward step B: X[f = i + 16*k1] in reg k1 ----
    fft16v<-1>(X);
    __syncthreads();   // plane reads complete before IPAD (aliased) writes

    // ---- intensity: combine modes via one shuffle, scatter to skewed IPAD ----
    {
        float* ipf = SMf + IPB_F + fr * IPS_F;
        #pragma unroll
        for (int k1 = 0; k1 < 16; ++k1) {
            float v = X[k1].x * X[k1].x + X[k1].y * X[k1].y;
            v += __shfl_xor(v, 16);        // mode sum
            if (!md && k1 < 8) {
                const int f = i + 16 * k1, p = f + PAD;
                ipf[p + (p >> 3)] = v;
                if (f < PAD) { const int p2 = f + 276; ipf[p2 + (p2 >> 3)] = v; }
            }
            if (md && k1 >= 8) {
                const int f = i + 16 * k1, p = f + PAD;
                ipf[p + (p >> 3)] = v;
                if (f >= 236) { const int p3 = f - 236; ipf[p3 + (p3 >> 3)] = v; }
            }
        }
    }
    __syncthreads();

    // ---- FIR: thread u of frame frq -> outputs 8u..8u+7 (packed output pairs) ----
    {
        const int u   = tid & 31;
        const int frq = tid >> 5;
        int g2 = blockIdx.x * 2 + frq;
        if (g2 >= G) g2 = G - 1;
        const int b2 = g2 / steps;
        const float* ipb = SMf + IPB_F + frq * IPS_F + 9 * u;   // 9u = 8u + (8u>>3) skew
        float w_[9];
        #pragma unroll
        for (int j = 0; j < 9; ++j) w_[j] = ipb[j + (j >> 3)];
        v2f W2[8];
        #pragma unroll
        for (int ss = 0; ss < 8; ++ss) W2[ss] = mkv2(w_[ss], w_[ss + 1]);
        float carry = w_[8];
        v2f pr[4], pq[4];
        #pragma unroll
        for (int m = 0; m < 4; ++m) { pr[m] = mkv2(0.f, 0.f); pq[m] = mkv2(0.f, 0.f); }
        #pragma unroll
        for (int t = 0; t < 41; ++t) {
            const v2f h2r = SM2[HRB + t];   // {hr,hr} broadcast
            const v2f h2i = SM2[HIB + t];   // {hi,hi}
            #pragma unroll
            for (int m = 0; m < 4; ++m) {
                const v2f wp = W2[(t + 2 * m) & 7];
                pr[m] += wp * h2r;
                pq[m] += wp * h2i;
            }
            if (t < 39) {
                const int j = t + 9;
                const float nw = ipb[j + (j >> 3)];
                W2[(t + 8) & 7] = mkv2(carry, nw);
                carry = nw;
            }
        }
        const float P = exp2f(task_info[4 * b2] * 0.33219280948873623f) * 0.5f;
        // skewed C: c[f] at v2f idx f + 2*(f>>4); per-thread base 8u + 2*(u>>1)
        float4* cp = (float4*)&SM2[frq * CFS + 8 * u + 2 * (u >> 1)];
        #pragma unroll
        for (int m = 0; m < 4; ++m)
            cp[m] = make_float4(1.0f - P * pq[m].x, P * pr[m].x,
                                1.0f - P * pq[m].y, P * pr[m].y);
    }
    __syncthreads();

    // ---- modulate X[f] *= c[f]  (skewed read: f=i+16k1 -> idx i+18k1) ----
    {
        #pragma unroll
        for (int k1 = 0; k1 < 16; ++k1) {
            const v2f c = SM2[fr * CFS + i + 18 * k1];
            X[k1] = cmul2(X[k1], c);
        }
    }

    // ---- inverse step A + conj twiddle ----
    fft16v<1>(X);
    twiddle4(X, mkv2(cb, -sb));
    __syncthreads();   // C reads done; plane region reusable

    // ---- inverse transpose ----
    {
        float4* rowp = (float4*)&SM2[tb2 + i * RS];
        #pragma unroll
        for (int k = 0; k < 16; k += 2)
            rowp[k >> 1] = make_float4(X[k].x, X[k].y, X[k + 1].x, X[k + 1].y);
    }
    __syncthreads();
    #pragma unroll
    for (int k2 = 0; k2 < 16; ++k2) X[k2] = SM2[tb2 + k2 * RS + i];

    // ---- inverse step B: y[i + 16*n2] (x256) ----
    fft16v<1>(X);

    // ---- in-block exchange: fr0 tail (n >= 216) -> LDS for fr1's head ----
    if (valid && fr == 0) {
        #pragma unroll
        for (int n2 = 13; n2 < 16; ++n2) {
            const int n = i + 16 * n2;
            if (n >= HOP) SM2[EXB + (n - HOP) * 2 + md] = X[n2];
        }
    }
    __syncthreads();

    // ---- OLA + crop ----
    if (valid) {
        const int Lout = L - 2 * PAD;
        float* obase = out + (size_t)b * Lout * 4 + md * 2;
        #pragma unroll
        for (int n2 = 0; n2 < 16; ++n2) {
            const int n  = i + 16 * n2;
            const int la = l0 + n;
            if (la < PAD || la >= L - PAD) continue;
            const bool head = (n < NFFT - HOP) && (s > 0);
            const bool tail = (n >= HOP) && (s + 1 < steps);
            float* p = obase + (size_t)(la - PAD) * 4;
            const v2f v = X[n2];
            if (tail) {
                if (fr == 0) continue;                     // delivered via EXB
                const float sc = 0.5f * (1.0f / 256.0f);   // cross-block: atomic half
                atomicAdd(p, v.x * sc); atomicAdd(p + 1, v.y * sc);
            } else if (head) {
                if (fr == 1) {                             // in-block combine, plain store
                    const v2f o = SM2[EXB + n * 2 + md];
                    const float sc = 0.5f * (1.0f / 256.0f);
                    *(float2*)p = make_float2((v.x + o.x) * sc, (v.y + o.y) * sc);
                } else {                                   // cross-block: atomic half
                    const float sc = 0.5f * (1.0f / 256.0f);
                    atomicAdd(p, v.x * sc); atomicAdd(p + 1, v.y * sc);
                }
            } else {
                const float sc = 1.0f / 256.0f;
                *(float2*)p = make_float2(v.x * sc, v.y * sc);
            }
        }
    }
}

extern "C" void kernel_launch(void* const* d_in, const int* in_sizes, int n_in,
                              void* d_out, int out_size, void* d_ws, size_t ws_size,
                              hipStream_t stream) {
    const float* x_real    = (const float*)d_in[0];
    const float* x_imag    = (const float*)d_in[1];
    const float* task_info = (const float*)d_in[2];
    const float* h_real    = (const float*)d_in[3];
    const float* h_imag    = (const float*)d_in[4];

    const int B     = in_sizes[2] / 4;
    const int L     = in_sizes[0] / (B * 2);
    const int steps = (L - NFFT) / HOP + 1;
    const int G     = B * steps;
    const int Lout  = L - 2 * PAD;

    const int nb = (steps - 1) / 2;
    if (nb > 0) {
        const int total4 = B * nb * 40;
        const int zb = (total4 + 255) / 256;
        zero_overlap<<<zb, 256, 0, stream>>>((float4*)d_out, B, steps, Lout);
    }

    eq_pbc_kernel<<<(G + 1) / 2, 64, 0, stream>>>(
        x_real, x_imag, task_info, h_real, h_imag, (float*)d_out, B, L, steps);
}

// Round 4
// 103.632 us; speedup vs baseline: 1.0114x; 1.0114x over previous
//
#include <hip/hip_runtime.h>
#include <hip/hip_fp16.h>
#include <math.h>

constexpr int NFFT = 256;
constexpr int HOP  = 216;
constexpr int PAD  = 20;

typedef float v2f __attribute__((ext_vector_type(2)));

// LDS layout in v2f units (8 B each); phases alias time-disjointly:
//  plane [0..1024)   : 4 fm x (16 rows x 16 cols, XOR-swizzled col ^= (row&7)<<1)
//  C     [0..576)    : skewed complex c, stride 288/frame   (aliases plane; used FIR->modulate)
//  IPAD  [576..912)  : skewed padded intensity (floats [1152..1824)), 336 floats/frame
//                      (aliases plane upper half; used intensity->FIR)
//  EXB   [0..80)     : fr0 tail exchange (aliases plane; written after last plane read)
//  h     : NOT in LDS -- wave-uniform scalar loads (s_load, K$-warm)
constexpr int RS    = 16;     // transpose row stride (v2f)
constexpr int PLF   = 256;    // per-fm plane size (v2f)
constexpr int CFS   = 288;    // C stride per frame (v2f)
constexpr int IPB_F = 1152;   // IPAD base (float idx)
constexpr int IPS_F = 336;    // IPAD stride per frame (floats)
constexpr int EXB   = 0;      // exchange base (v2f idx), aliases plane after final read
constexpr int SMV   = 1024;   // total v2f = 8192 B exactly

__device__ __forceinline__ v2f mkv2(float a, float b) { v2f r; r.x = a; r.y = b; return r; }

// complex mul: {a.x*b.x - a.y*b.y, a.x*b.y + a.y*b.x} -> pk_mul + pk_fma (op_sel/neg folded)
__device__ __forceinline__ v2f cmul2(v2f a, v2f b) {
    return a.xx * b + a.yy * mkv2(-b.y, b.x);
}

constexpr float TC16[10] = {1.f, 0.92387953f, 0.70710678f, 0.38268343f, 0.f,
                            -0.38268343f, -0.70710678f, -0.92387953f, -1.f, -0.92387953f};
constexpr float TS16[10] = {0.f, 0.38268343f, 0.70710678f, 0.92387953f, 1.f,
                            0.92387953f, 0.70710678f, 0.38268343f, 0.f, -0.38268343f};

// In-register 16-point DFT on (re,im) pairs, natural order in/out.
template<int SGN>
__device__ __forceinline__ void fft16v(v2f x[16]) {
    v2f t[4][4];
    #pragma unroll
    for (int n1 = 0; n1 < 4; ++n1) {
        v2f a = x[n1], b = x[n1 + 4], c = x[n1 + 8], d = x[n1 + 12];
        v2f A = a + c, B = a - c, C = b + d, D = b - d;
        v2f jD = mkv2(-D.y, D.x);
        t[n1][0] = A + C;
        t[n1][2] = A - C;
        if (SGN < 0) { t[n1][1] = B - jD; t[n1][3] = B + jD; }
        else         { t[n1][1] = B + jD; t[n1][3] = B - jD; }
    }
    #pragma unroll
    for (int n1 = 1; n1 < 4; ++n1) {
        #pragma unroll
        for (int k2 = 1; k2 < 4; ++k2) {
            const int m = n1 * k2;
            const float wr = TC16[m], wi = (float)SGN * TS16[m];
            v2f v = t[n1][k2];
            t[n1][k2] = wr * v + wi * mkv2(-v.y, v.x);
        }
    }
    #pragma unroll
    for (int k2 = 0; k2 < 4; ++k2) {
        v2f a = t[0][k2], b = t[1][k2], c = t[2][k2], d = t[3][k2];
        v2f A = a + c, B = a - c, C = b + d, D = b - d;
        v2f jD = mkv2(-D.y, D.x);
        x[k2]      = A + C;
        x[k2 + 8]  = A - C;
        if (SGN < 0) { x[k2 + 4] = B - jD; x[k2 + 12] = B + jD; }
        else         { x[k2 + 4] = B + jD; x[k2 + 12] = B - jD; }
    }
}

// x[k] *= w1^k via power tree + 4 parallel chains.
__device__ __forceinline__ void twiddle4(v2f x[16], v2f w1) {
    const v2f w2 = cmul2(w1, w1);
    const v2f w4 = cmul2(w2, w2);
    const v2f w8 = cmul2(w4, w4);
    x[1] = cmul2(x[1], w1);
    x[2] = cmul2(x[2], w2);
    x[3] = cmul2(x[3], cmul2(w2, w1));
    v2f wk = w4;
    x[4] = cmul2(x[4], wk);
    wk = cmul2(wk, w1); x[5] = cmul2(x[5], wk);
    wk = cmul2(wk, w1); x[6] = cmul2(x[6], wk);
    wk = cmul2(wk, w1); x[7] = cmul2(x[7], wk);
    v2f wm = w8;
    x[8] = cmul2(x[8], wm);
    wm = cmul2(wm, w1); x[9]  = cmul2(x[9],  wm);
    wm = cmul2(wm, w1); x[10] = cmul2(x[10], wm);
    wm = cmul2(wm, w1); x[11] = cmul2(x[11], wm);
    v2f wn = cmul2(w8, w4);
    x[12] = cmul2(x[12], wn);
    wn = cmul2(wn, w1); x[13] = cmul2(x[13], wn);
    wn = cmul2(wn, w1); x[14] = cmul2(x[14], wn);
    wn = cmul2(wn, w1); x[15] = cmul2(x[15], wn);
}

// Zero only the EVEN-s overlap stripes (the only remaining atomicAdd targets).
__global__ __launch_bounds__(256)
void zero_overlap(float4* __restrict__ out4, int B, int steps, int Lout) {
    const int nb = (steps - 1) / 2;            // even boundaries s = 2,4,...,2*nb
    const int total = B * nb * 40;
    for (int idx = blockIdx.x * 256 + threadIdx.x; idx < total; idx += gridDim.x * 256) {
        const int j  = idx / 40;
        const int r4 = idx - j * 40;
        const int b  = j / nb;
        const int k  = j - b * nb;
        const int s  = 2 * (k + 1);
        out4[(size_t)b * Lout + (size_t)s * HOP - PAD + r4] = make_float4(0.f, 0.f, 0.f, 0.f);
    }
}

// ONE WAVE per block: 64 threads = 2 frames x 2 modes x 16 lanes.
// The two frames are always (b, s) and (b, s+1): the odd-s boundary between
// them is resolved in-block via LDS (no atomics, no pre-zeroing).
__global__ __launch_bounds__(64)
void eq_pbc_kernel(const float* __restrict__ x_real,
                   const float* __restrict__ x_imag,
                   const float* __restrict__ task_info,
                   const float* __restrict__ h_real,
                   const float* __restrict__ h_imag,
                   float* __restrict__ out,
                   int B, int L, int steps)
{
    __shared__ __align__(16) v2f SM2[SMV];
    float* SMf = (float*)SM2;

    const int tid = threadIdx.x;
    const int i   = tid & 15;
    const int fm  = tid >> 4;     // 0..3
    const int fr  = fm >> 1;      // frame-local 0..1
    const int md  = fm & 1;

    const int G = B * steps;
    int g = blockIdx.x * 2 + fr;
    const bool valid = (g < G);
    if (!valid) g = G - 1;
    const int b  = g / steps;
    const int s  = g - b * steps;
    const int l0 = s * HOP;

    float sb, cb;
    __sincosf(-6.2831853071795864f * (1.0f / 256.0f) * (float)i, &sb, &cb);

    // ---- load: thread holds x[l0 + i + 16*n2] for its (frame, mode) ----
    v2f X[16];
    {
        const size_t base = ((size_t)b * L + l0) * 2 + (size_t)(2 * i + md);
        #pragma unroll
        for (int n2 = 0; n2 < 16; ++n2)
            X[n2] = mkv2(x_real[base + 32 * n2], x_imag[base + 32 * n2]);
    }

    // ---- forward step A + twiddle W256^{i*k2} ----
    fft16v<-1>(X);
    twiddle4(X, mkv2(cb, sb));

    // ---- forward transpose (swizzled plane: phys col = logical col ^ ((row&7)<<1)) ----
    const int tb2 = fm * PLF;
    const int swi = (i & 7) << 1;
    {
        float4* rowp = (float4*)&SM2[tb2 + i * RS];
        #pragma unroll
        for (int k = 0; k < 16; k += 2)
            rowp[(k ^ swi) >> 1] = make_float4(X[k].x, X[k].y, X[k + 1].x, X[k + 1].y);
    }
    __syncthreads();
    #pragma unroll
    for (int n1 = 0; n1 < 16; ++n1)
        X[n1] = SM2[tb2 + n1 * RS + (i ^ ((n1 & 7) << 1))];

    // ---- forward step B: X[f = i + 16*k1] in reg k1 ----
    fft16v<-1>(X);
    __syncthreads();   // plane reads complete before IPAD (aliased) writes

    // ---- intensity: combine modes via one shuffle, scatter to skewed IPAD ----
    {
        float* ipf = SMf + IPB_F + fr * IPS_F;
        #pragma unroll
        for (int k1 = 0; k1 < 16; ++k1) {
            float v = X[k1].x * X[k1].x + X[k1].y * X[k1].y;
            v += __shfl_xor(v, 16);        // mode sum
            if (!md && k1 < 8) {
                const int f = i + 16 * k1, p = f + PAD;
                ipf[p + (p >> 3)] = v;
                if (f < PAD) { const int p2 = f + 276; ipf[p2 + (p2 >> 3)] = v; }
            }
            if (md && k1 >= 8) {
                const int f = i + 16 * k1, p = f + PAD;
                ipf[p + (p >> 3)] = v;
                if (f >= 236) { const int p3 = f - 236; ipf[p3 + (p3 >> 3)] = v; }
            }
        }
    }
    __syncthreads();

    // ---- FIR: thread u of frame frq -> outputs 8u..8u+7 (packed output pairs) ----
    // h taps via wave-uniform scalar loads (s_load); VOP3P broadcasts scalar to both halves.
    {
        const int u   = tid & 31;
        const int frq = tid >> 5;
        int g2 = blockIdx.x * 2 + frq;
        if (g2 >= G) g2 = G - 1;
        const int b2 = g2 / steps;
        const float* ipb = SMf + IPB_F + frq * IPS_F + 9 * u;   // 9u = 8u + (8u>>3) skew
        float w_[9];
        #pragma unroll
        for (int j = 0; j < 9; ++j) w_[j] = ipb[j + (j >> 3)];
        v2f W2[8];
        #pragma unroll
        for (int ss = 0; ss < 8; ++ss) W2[ss] = mkv2(w_[ss], w_[ss + 1]);
        float carry = w_[8];
        v2f pr[4], pq[4];
        #pragma unroll
        for (int m = 0; m < 4; ++m) { pr[m] = mkv2(0.f, 0.f); pq[m] = mkv2(0.f, 0.f); }
        #pragma unroll
        for (int t = 0; t < 41; ++t) {
            const float htr = h_real[t];    // uniform -> s_load
            const float hti = h_imag[t];
            #pragma unroll
            for (int m = 0; m < 4; ++m) {
                const v2f wp = W2[(t + 2 * m) & 7];
                pr[m] += wp * htr;
                pq[m] += wp * hti;
            }
            if (t < 39) {
                const int j = t + 9;
                const float nw = ipb[j + (j >> 3)];
                W2[(t + 8) & 7] = mkv2(carry, nw);
                carry = nw;
            }
        }
        const float P = exp2f(task_info[4 * b2] * 0.33219280948873623f) * 0.5f;
        // skewed C: c[f] at v2f idx f + 2*(f>>4); per-thread base 8u + 2*(u>>1)
        float4* cp = (float4*)&SM2[frq * CFS + 8 * u + 2 * (u >> 1)];
        #pragma unroll
        for (int m = 0; m < 4; ++m)
            cp[m] = make_float4(1.0f - P * pq[m].x, P * pr[m].x,
                                1.0f - P * pq[m].y, P * pr[m].y);
    }
    __syncthreads();

    // ---- modulate X[f] *= c[f]  (skewed read: f=i+16k1 -> idx i+18k1) ----
    {
        #pragma unroll
        for (int k1 = 0; k1 < 16; ++k1) {
            const v2f c = SM2[fr * CFS + i + 18 * k1];
            X[k1] = cmul2(X[k1], c);
        }
    }

    // ---- inverse step A + conj twiddle ----
    fft16v<1>(X);
    twiddle4(X, mkv2(cb, -sb));
    __syncthreads();   // C reads done; plane region reusable

    // ---- inverse transpose (same swizzled plane) ----
    {
        float4* rowp = (float4*)&SM2[tb2 + i * RS];
        #pragma unroll
        for (int k = 0; k < 16; k += 2)
            rowp[(k ^ swi) >> 1] = make_float4(X[k].x, X[k].y, X[k + 1].x, X[k + 1].y);
    }
    __syncthreads();
    #pragma unroll
    for (int k2 = 0; k2 < 16; ++k2)
        X[k2] = SM2[tb2 + k2 * RS + (i ^ ((k2 & 7) << 1))];

    // ---- inverse step B: y[i + 16*n2] (x256) ----
    fft16v<1>(X);

    // ---- in-block exchange: fr0 tail (n >= 216) -> LDS for fr1's head ----
    // EXB aliases plane[0..80): single wave => all plane reads (program-order
    // earlier instructions) complete before these writes issue.
    if (valid && fr == 0) {
        #pragma unroll
        for (int n2 = 13; n2 < 16; ++n2) {
            const int n = i + 16 * n2;
            if (n >= HOP) SM2[EXB + (n - HOP) * 2 + md] = X[n2];
        }
    }
    __syncthreads();

    // ---- OLA + crop ----
    if (valid) {
        const int Lout = L - 2 * PAD;
        float* obase = out + (size_t)b * Lout * 4 + md * 2;
        #pragma unroll
        for (int n2 = 0; n2 < 16; ++n2) {
            const int n  = i + 16 * n2;
            const int la = l0 + n;
            if (la < PAD || la >= L - PAD) continue;
            const bool head = (n < NFFT - HOP) && (s > 0);
            const bool tail = (n >= HOP) && (s + 1 < steps);
            float* p = obase + (size_t)(la - PAD) * 4;
            const v2f v = X[n2];
            if (tail) {
                if (fr == 0) continue;                     // delivered via EXB
                const float sc = 0.5f * (1.0f / 256.0f);   // cross-block: atomic half
                atomicAdd(p, v.x * sc); atomicAdd(p + 1, v.y * sc);
            } else if (head) {
                if (fr == 1) {                             // in-block combine, plain store
                    const v2f o = SM2[EXB + n * 2 + md];
                    const float sc = 0.5f * (1.0f / 256.0f);
                    *(float2*)p = make_float2((v.x + o.x) * sc, (v.y + o.y) * sc);
                } else {                                   // cross-block: atomic half
                    const float sc = 0.5f * (1.0f / 256.0f);
                    atomicAdd(p, v.x * sc); atomicAdd(p + 1, v.y * sc);
                }
            } else {
                const float sc = 1.0f / 256.0f;
                *(float2*)p = make_float2(v.x * sc, v.y * sc);
            }
        }
    }
}

extern "C" void kernel_launch(void* const* d_in, const int* in_sizes, int n_in,
                              void* d_out, int out_size, void* d_ws, size_t ws_size,
                              hipStream_t stream) {
    const float* x_real    = (const float*)d_in[0];
    const float* x_imag    = (const float*)d_in[1];
    const float* task_info = (const float*)d_in[2];
    const float* h_real    = (const float*)d_in[3];
    const float* h_imag    = (const float*)d_in[4];

    const int B     = in_sizes[2] / 4;
    const int L     = in_sizes[0] / (B * 2);
    const int steps = (L - NFFT) / HOP + 1;
    const int G     = B * steps;
    const int Lout  = L - 2 * PAD;

    const int nb = (steps - 1) / 2;
    if (nb > 0) {
        const int total4 = B * nb * 40;
        const int zb = (total4 + 255) / 256;
        zero_overlap<<<zb, 256, 0, stream>>>((float4*)d_out, B, steps, Lout);
    }

    eq_pbc_kernel<<<(G + 1) / 2, 64, 0, stream>>>(
        x_real, x_imag, task_info, h_real, h_imag, (float*)d_out, B, L, steps);
}